// Round 5
// baseline (90.315 us; speedup 1.0000x reference)
//
#include <hip/hip_runtime.h>
#include <hip/hip_bf16.h>
#include <math.h>

#define BATCH 16384
#define NF 26
#define ND 13
#define VOC 100000
#define KP0 448
#define KP1 416

typedef __bf16 bf16x8 __attribute__((ext_vector_type(8)));
typedef float f32x4 __attribute__((ext_vector_type(4)));
using bf16 = __hip_bfloat16;

__device__ __forceinline__ void gload_lds16(const void* g, void* l) {
  __builtin_amdgcn_global_load_lds(
      (const __attribute__((address_space(1))) void*)g,
      (__attribute__((address_space(3))) void*)l, 16, 0, 0);
}

// ---------- merged prep (weight transpose+cast) + gather/FM ----------
__global__ __launch_bounds__(256) void prep_gather_kernel(
    const float* __restrict__ w0, const float* __restrict__ w1,
    const float* __restrict__ w2, bf16* __restrict__ wt0,
    bf16* __restrict__ wt1, bf16* __restrict__ wt2,
    const int* __restrict__ xs, const float* __restrict__ xd,
    const float* __restrict__ emb1, const float* __restrict__ emb2,
    const float* __restrict__ wd, const float* __restrict__ biasp,
    bf16* __restrict__ h0, float* __restrict__ partial) {
  const int bid = blockIdx.x, tid = threadIdx.x;
  if (bid < 2080) {  // ---- prep: Wt[n][k] = W[k][n], zero-pad n>=400, k>=K
    const float* W; bf16* Wt; int K, KP, idx;
    if (bid < 728)       { W = w0; Wt = wt0; K = 429; KP = KP0; idx = bid * 256 + tid; }
    else if (bid < 1404) { W = w1; Wt = wt1; K = 400; KP = KP1; idx = (bid - 728) * 256 + tid; }
    else                 { W = w2; Wt = wt2; K = 400; KP = KP1; idx = (bid - 1404) * 256 + tid; }
    int k = idx % KP, n = idx / KP;
    float v = (k < K && n < 400) ? W[(size_t)k * 400 + n] : 0.f;
    Wt[idx] = __float2bfloat16(v);
    return;
  }
  // ---- gather + FM. One wave per sample.
  int gid = (bid - 2080) * 256 + tid;
  int b = gid >> 6;
  int lane = tid & 63;
  int fsub = lane >> 4;
  int e = lane & 15;
  float s_acc = 0.f, sq_acc = 0.f, lin = 0.f;
#pragma unroll
  for (int it = 0; it < 7; ++it) {
    int f = it * 4 + fsub;
    if (f < NF) {
      int idx = xs[b * NF + f];
      float v = emb2[((size_t)(f * VOC + idx)) * 16 + e];
      h0[(size_t)b * KP0 + f * 16 + e] = __float2bfloat16(v);
      s_acc += v;
      sq_acc += v * v;
      if (e == 0) lin += emb1[(size_t)f * VOC + idx];
    }
  }
  if (lane < 32) {
    float v = 0.f;
    if (lane < ND) { v = xd[b * ND + lane]; lin += v * wd[lane]; }
    h0[(size_t)b * KP0 + 416 + lane] = __float2bfloat16(v);
  }
  float s_tot = s_acc;
  s_tot += __shfl_xor(s_tot, 16);
  s_tot += __shfl_xor(s_tot, 32);
  float r0 = s_tot * s_tot;
  float r1 = sq_acc;
  float r2 = lin;
#pragma unroll
  for (int off = 1; off < 64; off <<= 1) {
    r0 += __shfl_xor(r0, off);
    r1 += __shfl_xor(r1, off);
    r2 += __shfl_xor(r2, off);
  }
  if (lane == 0) {
    float cross = 0.5f * (r0 * 0.25f - r1);
    partial[b] = biasp[0] + r2 + cross;
  }
}

// ---------- mid GEMM. Block: 64 rows x 208 cols (ch). 4 waves, col-disjoint
// tiles {4,3,3,3}, RT=4 row-tiles per wave (B-frag reused 4x).
// B k-slab (208x32 bf16, swizzled) double-buffered via global_load_lds.
// grid 512 -> 2 blocks/CU.
template <int KP>
__global__ __launch_bounds__(256) void mid_kernel(
    const bf16* __restrict__ A, const bf16* __restrict__ Wt,
    const float* __restrict__ bias, bf16* __restrict__ outH) {
  constexpr int NK = KP / 32;
  __shared__ __align__(16) bf16 slab[2][208 * 32];
  const int bid = blockIdx.x;
  const int ch = bid & 1;
  const int tid = threadIdx.x, w = tid >> 6, lane = tid & 63;
  const int r = lane & 15, g = lane >> 4;
  const int row0 = (bid >> 1) * 64;
  const int ncol0 = ch * 208;
  const char* wbase = (const char*)(Wt + (size_t)ncol0 * KP);

  auto stage = [&](int buf, int k) {
#pragma unroll
    for (int rd = 0; rd < 4; ++rd) {
      int c = rd * 256 + tid;
      if (c < 832) {
        int n = c >> 2, j = c & 3;
        int kc = j ^ ((n >> 1) & 3);
        gload_lds16(wbase + (size_t)n * (KP * 2) + k * 64 + kc * 16,
                    (char*)&slab[buf][0] + (rd * 256 + w * 64) * 16);
      }
    }
  };

  const int ntc = (w == 0) ? 4 : 3;           // col tiles per wave
  const int tb0 = (w == 0) ? 0 : 4 + (w - 1) * 3;

  const char* Ab = (const char*)(A + (size_t)(row0 + r) * KP) + g * 16;
  const size_t rtStride = (size_t)16 * KP * 2;
  bf16x8 aNext[4];
#pragma unroll
  for (int rt = 0; rt < 4; ++rt)
    aNext[rt] = *(const bf16x8*)(Ab + rt * rtStride);
  stage(0, 0);
  __syncthreads();

  f32x4 acc[4][4];
#pragma unroll
  for (int rt = 0; rt < 4; ++rt)
#pragma unroll
    for (int nt = 0; nt < 4; ++nt) acc[rt][nt] = (f32x4){0.f, 0.f, 0.f, 0.f};

  const int chunkoff = ((g ^ ((r >> 1) & 3)) << 4);
  int cur = 0;
  for (int k = 0; k < NK; ++k) {
    bf16x8 aCur[4];
#pragma unroll
    for (int rt = 0; rt < 4; ++rt) aCur[rt] = aNext[rt];
    if (k + 1 < NK) {
#pragma unroll
      for (int rt = 0; rt < 4; ++rt)
        aNext[rt] = *(const bf16x8*)(Ab + (k + 1) * 64 + rt * rtStride);
      stage(cur ^ 1, k + 1);
    }
    const char* sb = (const char*)&slab[cur][0] + r * 64 + chunkoff;
#pragma unroll
    for (int nt = 0; nt < 4; ++nt)
      if (nt < ntc) {
        bf16x8 bfr = *(const bf16x8*)(sb + (tb0 + nt) * 1024);
#pragma unroll
        for (int rt = 0; rt < 4; ++rt)
          acc[rt][nt] = __builtin_amdgcn_mfma_f32_16x16x32_bf16(aCur[rt], bfr, acc[rt][nt], 0, 0, 0);
      }
    __syncthreads();
    cur ^= 1;
  }

#pragma unroll
  for (int nt = 0; nt < 4; ++nt)
    if (nt < ntc) {
      int col = ncol0 + (tb0 + nt) * 16 + r;
      bool live = (col < 400);
      float bv = live ? bias[col] : 0.f;
#pragma unroll
      for (int rt = 0; rt < 4; ++rt)
#pragma unroll
        for (int q = 0; q < 4; ++q) {
          float v = live ? fmaxf(acc[rt][nt][q] + bv, 0.f) : 0.f;
          outH[(size_t)(row0 + rt * 16 + g * 4 + q) * KP1 + col] = __float2bfloat16(v);
        }
    }
}

// ---------- final GEMM + dot(fw) + sigmoid. Block: 32 rows x 416 cols.
// 4 waves, col tiles {7,7,6,6}, RT=2. grid 512 -> 2 blocks/CU.
__global__ __launch_bounds__(256) void fin_kernel(
    const bf16* __restrict__ A, const bf16* __restrict__ Wt,
    const float* __restrict__ bias, const float* __restrict__ fw,
    const float* __restrict__ partial, float* __restrict__ out) {
  constexpr int KP = KP1, NK = KP1 / 32;
  __shared__ __align__(16) bf16 slab[2][416 * 32];
  __shared__ float dr[128];
  const int bid = blockIdx.x;
  const int tid = threadIdx.x, w = tid >> 6, lane = tid & 63;
  const int r = lane & 15, g = lane >> 4;
  const int row0 = bid * 32;

  auto stage = [&](int buf, int k) {
#pragma unroll
    for (int rd = 0; rd < 7; ++rd) {
      int c = rd * 256 + tid;
      if (c < 1664) {
        int n = c >> 2, j = c & 3;
        int kc = j ^ ((n >> 1) & 3);
        gload_lds16((const char*)Wt + (size_t)n * (KP * 2) + k * 64 + kc * 16,
                    (char*)&slab[buf][0] + (rd * 256 + w * 64) * 16);
      }
    }
  };

  const int ntc = (w < 2) ? 7 : 6;
  const int tb0 = (w < 2) ? w * 7 : 14 + (w - 2) * 6;

  const char* Ab = (const char*)(A + (size_t)(row0 + r) * KP) + g * 16;
  const size_t rtStride = (size_t)16 * KP * 2;
  bf16x8 aNext[2];
#pragma unroll
  for (int rt = 0; rt < 2; ++rt)
    aNext[rt] = *(const bf16x8*)(Ab + rt * rtStride);
  stage(0, 0);
  __syncthreads();

  f32x4 acc[2][7];
#pragma unroll
  for (int rt = 0; rt < 2; ++rt)
#pragma unroll
    for (int nt = 0; nt < 7; ++nt) acc[rt][nt] = (f32x4){0.f, 0.f, 0.f, 0.f};

  const int chunkoff = ((g ^ ((r >> 1) & 3)) << 4);
  int cur = 0;
  for (int k = 0; k < NK; ++k) {
    bf16x8 aCur[2];
#pragma unroll
    for (int rt = 0; rt < 2; ++rt) aCur[rt] = aNext[rt];
    if (k + 1 < NK) {
#pragma unroll
      for (int rt = 0; rt < 2; ++rt)
        aNext[rt] = *(const bf16x8*)(Ab + (k + 1) * 64 + rt * rtStride);
      stage(cur ^ 1, k + 1);
    }
    const char* sb = (const char*)&slab[cur][0] + r * 64 + chunkoff;
#pragma unroll
    for (int nt = 0; nt < 7; ++nt)
      if (nt < ntc) {
        bf16x8 bfr = *(const bf16x8*)(sb + (tb0 + nt) * 1024);
#pragma unroll
        for (int rt = 0; rt < 2; ++rt)
          acc[rt][nt] = __builtin_amdgcn_mfma_f32_16x16x32_bf16(aCur[rt], bfr, acc[rt][nt], 0, 0, 0);
      }
    __syncthreads();
    cur ^= 1;
  }

  float pr[2][4] = {{0.f, 0.f, 0.f, 0.f}, {0.f, 0.f, 0.f, 0.f}};
#pragma unroll
  for (int nt = 0; nt < 7; ++nt)
    if (nt < ntc) {
      int col = (tb0 + nt) * 16 + r;
      if (col < 400) {
        float bv = bias[col], fv = fw[col];
#pragma unroll
        for (int rt = 0; rt < 2; ++rt)
#pragma unroll
          for (int q = 0; q < 4; ++q)
            pr[rt][q] += fmaxf(acc[rt][nt][q] + bv, 0.f) * fv;
      }
    }
#pragma unroll
  for (int rt = 0; rt < 2; ++rt)
#pragma unroll
    for (int q = 0; q < 4; ++q) {
      pr[rt][q] += __shfl_xor(pr[rt][q], 1);
      pr[rt][q] += __shfl_xor(pr[rt][q], 2);
      pr[rt][q] += __shfl_xor(pr[rt][q], 4);
      pr[rt][q] += __shfl_xor(pr[rt][q], 8);
    }
  if (r < 4) {
#pragma unroll
    for (int rt = 0; rt < 2; ++rt) {
      float v = (r == 0) ? pr[rt][0] : (r == 1) ? pr[rt][1]
              : (r == 2) ? pr[rt][2] : pr[rt][3];
      dr[w * 32 + rt * 16 + g * 4 + r] = v;
    }
  }
  __syncthreads();
  if (tid < 32) {
    float x = partial[row0 + tid] + dr[tid] + dr[32 + tid] + dr[64 + tid] + dr[96 + tid];
    out[row0 + tid] = 1.f / (1.f + expf(-x));
  }
}

extern "C" void kernel_launch(void* const* d_in, const int* in_sizes, int n_in,
                              void* d_out, int out_size, void* d_ws, size_t ws_size,
                              hipStream_t stream) {
  const int* xs = (const int*)d_in[0];
  const float* xd = (const float*)d_in[1];
  const float* emb1 = (const float*)d_in[2];
  const float* emb2 = (const float*)d_in[3];
  const float* wd = (const float*)d_in[4];
  const float* bias = (const float*)d_in[5];
  const float* w0 = (const float*)d_in[6];
  const float* b0 = (const float*)d_in[7];
  const float* w1 = (const float*)d_in[8];
  const float* b1 = (const float*)d_in[9];
  const float* w2 = (const float*)d_in[10];
  const float* b2 = (const float*)d_in[11];
  const float* fw = (const float*)d_in[12];
  float* out = (float*)d_out;

  char* ws = (char*)d_ws;
  float* partial = (float*)(ws + 0);        //  65536 B
  bf16* wt0 = (bf16*)(ws + 65536);          // 416*448*2 = 372736
  bf16* wt1 = (bf16*)(ws + 438272);         // 416*416*2 = 346112
  bf16* wt2 = (bf16*)(ws + 784384);         // 346112 -> 1130496
  bf16* h0  = (bf16*)(ws + 1130496);        // 16384*448*2 = 14680064
  bf16* h1  = (bf16*)(ws + 15810560);       // 16384*416*2 = 13631488
  bf16* h2  = h0;                           // h0 dead after layer 0

  prep_gather_kernel<<<2080 + BATCH / 4, 256, 0, stream>>>(
      w0, w1, w2, wt0, wt1, wt2, xs, xd, emb1, emb2, wd, bias, h0, partial);

  mid_kernel<KP0><<<512, 256, 0, stream>>>(h0, wt0, b0, h1);
  mid_kernel<KP1><<<512, 256, 0, stream>>>(h1, wt1, b1, h2);
  fin_kernel<<<512, 256, 0, stream>>>(h2, wt2, b2, fw, partial, out);
}

// Round 6
// 89.626 us; speedup vs baseline: 1.0077x; 1.0077x over previous
//
#include <hip/hip_runtime.h>
#include <hip/hip_bf16.h>
#include <math.h>

#define BATCH 16384
#define NF 26
#define ND 13
#define VOC 100000
#define KP0 448
#define KP1 416

typedef __bf16 bf16x8 __attribute__((ext_vector_type(8)));
typedef float f32x4 __attribute__((ext_vector_type(4)));
using bf16 = __hip_bfloat16;
typedef unsigned short u16;

__device__ __forceinline__ void gload_lds16(const void* g, void* l) {
  __builtin_amdgcn_global_load_lds(
      (const __attribute__((address_space(1))) void*)g,
      (__attribute__((address_space(3))) void*)l, 16, 0, 0);
}

__device__ __forceinline__ u16 f2bu(float v) {
  union { __hip_bfloat16 b; u16 u; } cv;
  cv.b = __float2bfloat16(v);
  return cv.u;
}

// ---------- weight transpose+cast: Wt[n][k], 416 rows, zero-pad (R4-verbatim)
__global__ void prep_kernel(const float* __restrict__ w0, const float* __restrict__ w1,
                            const float* __restrict__ w2, bf16* __restrict__ wt0,
                            bf16* __restrict__ wt1, bf16* __restrict__ wt2) {
  int bid = blockIdx.x, tid = threadIdx.x;
  const float* W; bf16* Wt; int K, KP, idx;
  if (bid < 728)       { W = w0; Wt = wt0; K = 429; KP = KP0; idx = bid * 256 + tid; }
  else if (bid < 1404) { W = w1; Wt = wt1; K = 400; KP = KP1; idx = (bid - 728) * 256 + tid; }
  else                 { W = w2; Wt = wt2; K = 400; KP = KP1; idx = (bid - 1404) * 256 + tid; }
  int k = idx % KP, n = idx / KP;
  float v = (k < K && n < 400) ? W[(size_t)k * 400 + n] : 0.f;
  Wt[idx] = __float2bfloat16(v);
}

// ---------- fused gather + FM + layer-0 GEMM ----------
// Block: 64 samples x 208 cols (ch = bid&1). 4 waves in 2x2: rg=w>>1 (32 rows),
// cg=w&1 (7/6 col tiles). A gathered from emb2 per k-step into a small
// double-buffered LDS slab (issue-early/write-late, hidden under MFMA).
// FM stats accumulated in registers on the gathered f32 values.
__global__ __launch_bounds__(256) void gm0_kernel(
    const int* __restrict__ xs, const float* __restrict__ xd,
    const float* __restrict__ emb1, const float* __restrict__ emb2,
    const float* __restrict__ wd, const float* __restrict__ biasp,
    const bf16* __restrict__ wt0, const float* __restrict__ b0,
    bf16* __restrict__ outH, float* __restrict__ partial) {
  __shared__ __align__(16) bf16 slabB[2][208 * 32];   // 26624 B
  __shared__ __align__(16) bf16 slabA[2][64 * 32];    // 8192 B
  __shared__ int xs_lds[64 * NF];                     // 6656 B
  __shared__ float statS[4][64][8];                   // 8192 B
  __shared__ float statQ[4][64];                      // 1024 B
  __shared__ float statL[2][64];                      // 512 B
  const int bid = blockIdx.x;
  const int ch = bid & 1;
  const int row0 = (bid >> 1) * 64;
  const int tid = threadIdx.x, w = tid >> 6, lane = tid & 63;
  const int r = lane & 15, g = lane >> 4;
  const int rg = w >> 1, cg = w & 1;
  const int ntc = 7 - cg;
  const int tb0 = cg * 7;
  const char* wbase = (const char*)(wt0 + (size_t)(ch * 208) * KP0);

  // gather mapping: thread -> (row, feature-bit, half-row of 8 elems)
  const int grow = tid & 63, fbit = (tid >> 6) & 1, half = tid >> 7;
  const int awbyte = grow * 64 + (((fbit * 2 + half) ^ ((grow >> 1) & 3)) << 4);

  auto stageB = [&](int buf, int k) {
#pragma unroll
    for (int rd = 0; rd < 4; ++rd) {
      int c = rd * 256 + tid;
      if (c < 832) {
        int n = c >> 2, j = c & 3;
        int kc = j ^ ((n >> 1) & 3);
        gload_lds16(wbase + (size_t)n * (KP0 * 2) + k * 64 + kc * 16,
                    (char*)&slabB[buf][0] + (rd * 256 + w * 64) * 16);
      }
    }
  };

  // xs block is contiguous: 64*26 ints = 416 int4
  {
    const int4* src = (const int4*)(xs + (size_t)row0 * NF);
    int4* dst = (int4*)xs_lds;
    for (int i = tid; i < 416; i += 256) dst[i] = src[i];
  }
  stageB(0, 0);
  __syncthreads();

  float sv0 = 0.f, sv1 = 0.f, sv2 = 0.f, sv3 = 0.f;
  float sv4 = 0.f, sv5 = 0.f, sv6 = 0.f, sv7 = 0.f;
  float sq = 0.f, lin = 0.f;

  auto accumStats = [&](const float4& e0, const float4& e1) {
    sv0 += e0.x; sv1 += e0.y; sv2 += e0.z; sv3 += e0.w;
    sv4 += e1.x; sv5 += e1.y; sv6 += e1.z; sv7 += e1.w;
    sq += e0.x*e0.x + e0.y*e0.y + e0.z*e0.z + e0.w*e0.w
        + e1.x*e1.x + e1.y*e1.y + e1.z*e1.z + e1.w*e1.w;
  };
  auto writeA = [&](int buf, const float4& e0, const float4& e1) {
    union { bf16x8 v; u16 u[8]; } t;
    t.u[0] = f2bu(e0.x); t.u[1] = f2bu(e0.y); t.u[2] = f2bu(e0.z); t.u[3] = f2bu(e0.w);
    t.u[4] = f2bu(e1.x); t.u[5] = f2bu(e1.y); t.u[6] = f2bu(e1.z); t.u[7] = f2bu(e1.w);
    *(bf16x8*)((char*)&slabA[buf][0] + awbyte) = t.v;
  };

  // prologue: gather features {0,1} into slabA[0]
  {
    int f = fbit;
    int idx = xs_lds[grow * NF + f];
    const float* gp = emb2 + ((size_t)f * VOC + idx) * 16 + half * 8;
    float4 e0 = *(const float4*)gp;
    float4 e1 = *(const float4*)(gp + 4);
    if (half == 0) lin += emb1[(size_t)f * VOC + idx];
    accumStats(e0, e1);
    writeA(0, e0, e1);
  }
  __syncthreads();

  f32x4 acc[2][7];
#pragma unroll
  for (int rt = 0; rt < 2; ++rt)
#pragma unroll
    for (int nt = 0; nt < 7; ++nt) acc[rt][nt] = (f32x4){0.f, 0.f, 0.f, 0.f};

  const int ardswz = ((g ^ ((r >> 1) & 3)) << 4);
  for (int s = 0; s < 14; ++s) {
    // issue next-step gather loads (consumed late this step)
    float4 e0, e1; float l1 = 0.f;
    bool have = false, isStat = false;
    if (s < 12) {
      int f = 2 * (s + 1) + fbit;
      int idx = xs_lds[grow * NF + f];
      const float* gp = emb2 + ((size_t)f * VOC + idx) * 16 + half * 8;
      e0 = *(const float4*)gp;
      e1 = *(const float4*)(gp + 4);
      if (half == 0) l1 = emb1[(size_t)f * VOC + idx];
      have = true; isStat = true;
    } else if (s == 12) {
      float tv[8];
#pragma unroll
      for (int jj = 0; jj < 8; ++jj) {
        int c = fbit * 16 + half * 8 + jj;
        tv[jj] = (c < ND) ? xd[(size_t)(row0 + grow) * ND + c] : 0.f;
      }
      e0 = make_float4(tv[0], tv[1], tv[2], tv[3]);
      e1 = make_float4(tv[4], tv[5], tv[6], tv[7]);
      have = true;
    }
    if (s + 1 < 14) stageB((s + 1) & 1, s + 1);

    // compute
    bf16x8 a[2];
#pragma unroll
    for (int rt = 0; rt < 2; ++rt)
      a[rt] = *(const bf16x8*)((char*)&slabA[s & 1][0] +
                               (rg * 32 + rt * 16 + r) * 64 + ardswz);
    const char* sb = (const char*)&slabB[s & 1][0] + r * 64 + ardswz;
#pragma unroll
    for (int nt = 0; nt < 7; ++nt)
      if (nt < ntc) {
        bf16x8 bfr = *(const bf16x8*)(sb + (tb0 + nt) * 1024);
#pragma unroll
        for (int rt = 0; rt < 2; ++rt)
          acc[rt][nt] = __builtin_amdgcn_mfma_f32_16x16x32_bf16(a[rt], bfr, acc[rt][nt], 0, 0, 0);
      }

    // write next A (waits on the loads here, after MFMAs)
    if (have) {
      if (isStat) { accumStats(e0, e1); lin += l1; }
      writeA((s + 1) & 1, e0, e1);
    }
    __syncthreads();
  }

  // FM stats reduce -> partial
  {
    int sidx = half * 2 + fbit;
    *(float4*)&statS[sidx][grow][0] = make_float4(sv0, sv1, sv2, sv3);
    *(float4*)&statS[sidx][grow][4] = make_float4(sv4, sv5, sv6, sv7);
    statQ[sidx][grow] = sq;
    if (half == 0) statL[fbit][grow] = lin;
  }
  __syncthreads();
  if (ch == 0 && tid < 64) {
    int row = tid;
    float s2 = 0.f, qq = 0.f;
#pragma unroll
    for (int h = 0; h < 2; ++h)
#pragma unroll
      for (int eo = 0; eo < 8; ++eo) {
        float se = statS[h * 2][row][eo] + statS[h * 2 + 1][row][eo];
        s2 += se * se;
      }
#pragma unroll
    for (int j = 0; j < 4; ++j) qq += statQ[j][row];
    float li = statL[0][row] + statL[1][row];
#pragma unroll
    for (int d = 0; d < ND; ++d)
      li += xd[(size_t)(row0 + row) * ND + d] * wd[d];
    partial[row0 + row] = biasp[0] + li + 0.5f * (s2 - qq);
  }

  // epilogue: relu(acc + b0) -> outH (KP1 stride, zero cols >= 400)
#pragma unroll
  for (int nt = 0; nt < 7; ++nt)
    if (nt < ntc) {
      int col = ch * 208 + (tb0 + nt) * 16 + r;
      bool live = (col < 400);
      float bv = live ? b0[col] : 0.f;
#pragma unroll
      for (int rt = 0; rt < 2; ++rt)
#pragma unroll
        for (int q = 0; q < 4; ++q) {
          float v = live ? fmaxf(acc[rt][nt][q] + bv, 0.f) : 0.f;
          outH[(size_t)(row0 + rg * 32 + rt * 16 + g * 4 + q) * KP1 + col] = __float2bfloat16(v);
        }
    }
}

// ---------- mid GEMM (R4-verbatim). Block: 64 rows x 208 cols, 4 waves x 16 rows.
template <int KP>
__global__ __launch_bounds__(256) void mid_kernel(
    const bf16* __restrict__ A, const bf16* __restrict__ Wt,
    const float* __restrict__ bias, bf16* __restrict__ outH) {
  constexpr int NK = KP / 32;
  __shared__ __align__(16) bf16 slab[2][208 * 32];
  const int bid = blockIdx.x;
  const int ch = bid & 1;
  const int tid = threadIdx.x, w = tid >> 6, lane = tid & 63;
  const int r = lane & 15, g = lane >> 4;
  const int row0 = (bid >> 1) * 64 + w * 16;
  const int ncol0 = ch * 208;
  const char* wbase = (const char*)(Wt + (size_t)ncol0 * KP);

  auto stage = [&](int buf, int k) {
#pragma unroll
    for (int rd = 0; rd < 4; ++rd) {
      int c = rd * 256 + tid;
      if (c < 832) {
        int n = c >> 2, j = c & 3;
        int kc = j ^ ((n >> 1) & 3);
        gload_lds16(wbase + (size_t)n * (KP * 2) + k * 64 + kc * 16,
                    (char*)&slab[buf][0] + (rd * 256 + w * 64) * 16);
      }
    }
  };

  const char* Ab = (const char*)(A + (size_t)(row0 + r) * KP) + g * 16;
  bf16x8 aNext = *(const bf16x8*)(Ab);
  stage(0, 0);
  __syncthreads();

  f32x4 acc[13];
#pragma unroll
  for (int nt = 0; nt < 13; ++nt) acc[nt] = (f32x4){0.f, 0.f, 0.f, 0.f};

  const int chunkoff = ((g ^ ((r >> 1) & 3)) << 4);
  int cur = 0;
  for (int k = 0; k < NK; ++k) {
    bf16x8 aCur = aNext;
    if (k + 1 < NK) {
      aNext = *(const bf16x8*)(Ab + (k + 1) * 64);
      stage(cur ^ 1, k + 1);
    }
    const char* sb = (const char*)&slab[cur][0] + r * 64 + chunkoff;
#pragma unroll
    for (int nt = 0; nt < 13; ++nt) {
      bf16x8 b = *(const bf16x8*)(sb + nt * 1024);
      acc[nt] = __builtin_amdgcn_mfma_f32_16x16x32_bf16(aCur, b, acc[nt], 0, 0, 0);
    }
    __syncthreads();
    cur ^= 1;
  }

#pragma unroll
  for (int nt = 0; nt < 13; ++nt) {
    int col = ncol0 + nt * 16 + r;
    bool live = (col < 400);
    float bv = live ? bias[col] : 0.f;
#pragma unroll
    for (int q = 0; q < 4; ++q) {
      float v = live ? fmaxf(acc[nt][q] + bv, 0.f) : 0.f;
      outH[(size_t)(row0 + g * 4 + q) * KP1 + col] = __float2bfloat16(v);
    }
  }
}

// ---------- final GEMM + dot(fw) + sigmoid (R5-fin, k-loop == R4). 32 rows/block.
__global__ __launch_bounds__(256) void fin_kernel(
    const bf16* __restrict__ A, const bf16* __restrict__ Wt,
    const float* __restrict__ bias, const float* __restrict__ fw,
    const float* __restrict__ partial, float* __restrict__ out) {
  constexpr int KP = KP1, NK = KP1 / 32;
  __shared__ __align__(16) bf16 slab[2][416 * 32];
  __shared__ float dr[128];
  const int bid = blockIdx.x;
  const int tid = threadIdx.x, w = tid >> 6, lane = tid & 63;
  const int r = lane & 15, g = lane >> 4;
  const int row0 = bid * 32;

  auto stage = [&](int buf, int k) {
#pragma unroll
    for (int rd = 0; rd < 7; ++rd) {
      int c = rd * 256 + tid;
      if (c < 1664) {
        int n = c >> 2, j = c & 3;
        int kc = j ^ ((n >> 1) & 3);
        gload_lds16((const char*)Wt + (size_t)n * (KP * 2) + k * 64 + kc * 16,
                    (char*)&slab[buf][0] + (rd * 256 + w * 64) * 16);
      }
    }
  };

  const int ntc = (w < 2) ? 7 : 6;
  const int tb0 = (w < 2) ? w * 7 : 14 + (w - 2) * 6;

  const char* Ab = (const char*)(A + (size_t)(row0 + r) * KP) + g * 16;
  const size_t rtStride = (size_t)16 * KP * 2;
  bf16x8 aNext[2];
#pragma unroll
  for (int rt = 0; rt < 2; ++rt)
    aNext[rt] = *(const bf16x8*)(Ab + rt * rtStride);
  stage(0, 0);
  __syncthreads();

  f32x4 acc[2][7];
#pragma unroll
  for (int rt = 0; rt < 2; ++rt)
#pragma unroll
    for (int nt = 0; nt < 7; ++nt) acc[rt][nt] = (f32x4){0.f, 0.f, 0.f, 0.f};

  const int chunkoff = ((g ^ ((r >> 1) & 3)) << 4);
  int cur = 0;
  for (int k = 0; k < NK; ++k) {
    bf16x8 aCur[2];
#pragma unroll
    for (int rt = 0; rt < 2; ++rt) aCur[rt] = aNext[rt];
    if (k + 1 < NK) {
#pragma unroll
      for (int rt = 0; rt < 2; ++rt)
        aNext[rt] = *(const bf16x8*)(Ab + (k + 1) * 64 + rt * rtStride);
      stage(cur ^ 1, k + 1);
    }
    const char* sb = (const char*)&slab[cur][0] + r * 64 + chunkoff;
#pragma unroll
    for (int nt = 0; nt < 7; ++nt)
      if (nt < ntc) {
        bf16x8 bfr = *(const bf16x8*)(sb + (tb0 + nt) * 1024);
#pragma unroll
        for (int rt = 0; rt < 2; ++rt)
          acc[rt][nt] = __builtin_amdgcn_mfma_f32_16x16x32_bf16(aCur[rt], bfr, acc[rt][nt], 0, 0, 0);
      }
    __syncthreads();
    cur ^= 1;
  }

  float pr[2][4] = {{0.f, 0.f, 0.f, 0.f}, {0.f, 0.f, 0.f, 0.f}};
#pragma unroll
  for (int nt = 0; nt < 7; ++nt)
    if (nt < ntc) {
      int col = (tb0 + nt) * 16 + r;
      if (col < 400) {
        float bv = bias[col], fv = fw[col];
#pragma unroll
        for (int rt = 0; rt < 2; ++rt)
#pragma unroll
          for (int q = 0; q < 4; ++q)
            pr[rt][q] += fmaxf(acc[rt][nt][q] + bv, 0.f) * fv;
      }
    }
#pragma unroll
  for (int rt = 0; rt < 2; ++rt)
#pragma unroll
    for (int q = 0; q < 4; ++q) {
      pr[rt][q] += __shfl_xor(pr[rt][q], 1);
      pr[rt][q] += __shfl_xor(pr[rt][q], 2);
      pr[rt][q] += __shfl_xor(pr[rt][q], 4);
      pr[rt][q] += __shfl_xor(pr[rt][q], 8);
    }
  if (r < 4) {
#pragma unroll
    for (int rt = 0; rt < 2; ++rt) {
      float v = (r == 0) ? pr[rt][0] : (r == 1) ? pr[rt][1]
              : (r == 2) ? pr[rt][2] : pr[rt][3];
      dr[w * 32 + rt * 16 + g * 4 + r] = v;
    }
  }
  __syncthreads();
  if (tid < 32) {
    float x = partial[row0 + tid] + dr[tid] + dr[32 + tid] + dr[64 + tid] + dr[96 + tid];
    out[row0 + tid] = 1.f / (1.f + expf(-x));
  }
}

extern "C" void kernel_launch(void* const* d_in, const int* in_sizes, int n_in,
                              void* d_out, int out_size, void* d_ws, size_t ws_size,
                              hipStream_t stream) {
  const int* xs = (const int*)d_in[0];
  const float* xd = (const float*)d_in[1];
  const float* emb1 = (const float*)d_in[2];
  const float* emb2 = (const float*)d_in[3];
  const float* wd = (const float*)d_in[4];
  const float* bias = (const float*)d_in[5];
  const float* w0 = (const float*)d_in[6];
  const float* b0 = (const float*)d_in[7];
  const float* w1 = (const float*)d_in[8];
  const float* b1 = (const float*)d_in[9];
  const float* w2 = (const float*)d_in[10];
  const float* b2 = (const float*)d_in[11];
  const float* fw = (const float*)d_in[12];
  float* out = (float*)d_out;

  char* ws = (char*)d_ws;
  float* partial = (float*)(ws + 0);        //  65536 B
  bf16* wt0 = (bf16*)(ws + 65536);          // 416*448*2 = 372736
  bf16* wt1 = (bf16*)(ws + 438272);         // 416*416*2 = 346112
  bf16* wt2 = (bf16*)(ws + 784384);         // 346112 -> 1130496
  bf16* h1  = (bf16*)(ws + 1130496);        // 16384*416*2 = 13631488
  bf16* h2  = (bf16*)(ws + 14761984);       // 13631488

  prep_kernel<<<2080, 256, 0, stream>>>(w0, w1, w2, wt0, wt1, wt2);
  gm0_kernel<<<512, 256, 0, stream>>>(xs, xd, emb1, emb2, wd, bias, wt0, b0, h1, partial);
  mid_kernel<KP1><<<512, 256, 0, stream>>>(h1, wt1, b1, h2);
  fin_kernel<<<512, 256, 0, stream>>>(h2, wt2, b2, fw, partial, out);
}

// Round 7
// 78.772 us; speedup vs baseline: 1.1465x; 1.1378x over previous
//
#include <hip/hip_runtime.h>
#include <hip/hip_bf16.h>
#include <math.h>

#define BATCH 16384
#define NF 26
#define ND 13
#define VOC 100000
#define KP0 448
#define KP1 416
#define CS 80   // cols per N-slice
#define NSL 5   // N-slices (5*80 = 400 real cols)

typedef __bf16 bf16x8 __attribute__((ext_vector_type(8)));
typedef float f32x4 __attribute__((ext_vector_type(4)));
using bf16 = __hip_bfloat16;

__device__ __forceinline__ void gload_lds16(const void* g, void* l) {
  __builtin_amdgcn_global_load_lds(
      (const __attribute__((address_space(1))) void*)g,
      (__attribute__((address_space(3))) void*)l, 16, 0, 0);
}

// ---------- weight transpose+cast: Wt[n][k], 416 rows, zero-pad (R4-verbatim)
__global__ void prep_kernel(const float* __restrict__ w0, const float* __restrict__ w1,
                            const float* __restrict__ w2, bf16* __restrict__ wt0,
                            bf16* __restrict__ wt1, bf16* __restrict__ wt2) {
  int bid = blockIdx.x, tid = threadIdx.x;
  const float* W; bf16* Wt; int K, KP, idx;
  if (bid < 728)       { W = w0; Wt = wt0; K = 429; KP = KP0; idx = bid * 256 + tid; }
  else if (bid < 1404) { W = w1; Wt = wt1; K = 400; KP = KP1; idx = (bid - 728) * 256 + tid; }
  else                 { W = w2; Wt = wt2; K = 400; KP = KP1; idx = (bid - 1404) * 256 + tid; }
  int k = idx % KP, n = idx / KP;
  float v = (k < K && n < 400) ? W[(size_t)k * 400 + n] : 0.f;
  Wt[idx] = __float2bfloat16(v);
}

// ---------- gather + FM terms (R4-verbatim). One wave per sample. ----------
__global__ __launch_bounds__(256) void gather_fm_kernel(
    const int* __restrict__ xs, const float* __restrict__ xd,
    const float* __restrict__ emb1, const float* __restrict__ emb2,
    const float* __restrict__ wd, const float* __restrict__ bias,
    bf16* __restrict__ h0, float* __restrict__ partial) {
  int gid = blockIdx.x * blockDim.x + threadIdx.x;
  int b = gid >> 6;
  int lane = threadIdx.x & 63;
  int fsub = lane >> 4;
  int e = lane & 15;
  float s_acc = 0.f, sq_acc = 0.f, lin = 0.f;
#pragma unroll
  for (int it = 0; it < 7; ++it) {
    int f = it * 4 + fsub;
    if (f < NF) {
      int idx = xs[b * NF + f];
      float v = emb2[((size_t)(f * VOC + idx)) * 16 + e];
      h0[(size_t)b * KP0 + f * 16 + e] = __float2bfloat16(v);
      s_acc += v;
      sq_acc += v * v;
      if (e == 0) lin += emb1[(size_t)f * VOC + idx];
    }
  }
  if (lane < 32) {
    float v = 0.f;
    if (lane < ND) { v = xd[b * ND + lane]; lin += v * wd[lane]; }
    h0[(size_t)b * KP0 + 416 + lane] = __float2bfloat16(v);
  }
  float s_tot = s_acc;
  s_tot += __shfl_xor(s_tot, 16);
  s_tot += __shfl_xor(s_tot, 32);
  float r0 = s_tot * s_tot;
  float r1 = sq_acc;
  float r2 = lin;
#pragma unroll
  for (int off = 1; off < 64; off <<= 1) {
    r0 += __shfl_xor(r0, off);
    r1 += __shfl_xor(r1, off);
    r2 += __shfl_xor(r2, off);
  }
  if (lane == 0) {
    float cross = 0.5f * (r0 * 0.25f - r1);
    partial[b] = bias[0] + r2 + cross;
  }
}

// ---------- W-stationary streaming GEMM ----------
// Block: 80 cols (slice s) x 128 rows. W-slice [80][NK*32] loaded into LDS
// ONCE (NK sub-slabs [80][32], XOR-swizzled 16B chunks, via global_load_lds
// from inverse-swizzled source). K-loop: NO barriers, NO staging -- A streams
// from global into frags, B from read-only LDS. 4 waves x 32 rows (RT=2).
// grid 640 = 5 slices x 128 M-chunks, XCD-remapped so the 5 slices of an
// M-chunk share b%8 (A-rows XCD-local). 2 blocks/CU (LDS-limited).
// FINAL: per-slice dot partials -> dotb[s][row] (reduced by finish_kernel).
template <int NK, bool FINAL>
__global__ __launch_bounds__(256, 2) void gemm_kernel(
    const bf16* __restrict__ A, const bf16* __restrict__ Wt,
    const float* __restrict__ bias, bf16* __restrict__ outH,
    const float* __restrict__ fw, float* __restrict__ dotb) {
  constexpr int KP = NK * 32;
  extern __shared__ __align__(16) char smem[];
  const int b = blockIdx.x, tid = threadIdx.x;
  const int w = tid >> 6, lane = tid & 63, r = lane & 15, g = lane >> 4;
  const int lane8 = b & 7, hi = b >> 3;
  const int s = hi % NSL, mchunk = (hi / NSL) * 8 + lane8;
  const int row0 = mchunk * 128, col0 = s * CS;

  // ---- load W-slice once
  {
    const char* wbase = (const char*)(Wt + (size_t)col0 * KP);
    constexpr int T = NK * CS * 4;       // 16B chunks total
    constexpr int FULL = T >> 8, REM = T & 255;  // REM is 64 or 128: wave-uniform guard
    for (int rd = 0; rd <= FULL; ++rd) {
      if (rd < FULL || tid < REM) {
        int c = rd * 256 + tid;
        int kk = c / (CS * 4), rm = c - kk * (CS * 4);
        int n = rm >> 2, j = rm & 3;
        int kc = j ^ ((n >> 1) & 3);
        gload_lds16(wbase + (size_t)n * (KP * 2) + kk * 64 + kc * 16,
                    smem + (rd * 256 + w * 64) * 16);
      }
    }
  }
  __syncthreads();

  const char* Ab = (const char*)(A + (size_t)(row0 + w * 32 + r) * KP) + g * 16;
  const size_t rtS = (size_t)16 * KP * 2;

  f32x4 acc[2][NSL];
#pragma unroll
  for (int rt = 0; rt < 2; ++rt)
#pragma unroll
    for (int ct = 0; ct < NSL; ++ct) acc[rt][ct] = (f32x4){0.f, 0.f, 0.f, 0.f};

  const int swz = ((g ^ ((r >> 1) & 3)) << 4);
  for (int k = 0; k < NK; ++k) {
    bf16x8 a0 = *(const bf16x8*)(Ab + k * 64);
    bf16x8 a1 = *(const bf16x8*)(Ab + k * 64 + rtS);
    const char* sb = smem + k * (CS * 64) + r * 64 + swz;
#pragma unroll
    for (int ct = 0; ct < NSL; ++ct) {
      bf16x8 bfr = *(const bf16x8*)(sb + ct * 1024);
      acc[0][ct] = __builtin_amdgcn_mfma_f32_16x16x32_bf16(a0, bfr, acc[0][ct], 0, 0, 0);
      acc[1][ct] = __builtin_amdgcn_mfma_f32_16x16x32_bf16(a1, bfr, acc[1][ct], 0, 0, 0);
    }
  }

  if (!FINAL) {
#pragma unroll
    for (int ct = 0; ct < NSL; ++ct) {
      int col = col0 + ct * 16 + r;     // always < 400: no guard needed
      float bv = bias[col];
#pragma unroll
      for (int rt = 0; rt < 2; ++rt)
#pragma unroll
        for (int q = 0; q < 4; ++q) {
          float v = fmaxf(acc[rt][ct][q] + bv, 0.f);
          outH[(size_t)(row0 + w * 32 + rt * 16 + g * 4 + q) * KP1 + col] =
              __float2bfloat16(v);
        }
    }
  } else {
    float pr[2][4] = {{0.f, 0.f, 0.f, 0.f}, {0.f, 0.f, 0.f, 0.f}};
#pragma unroll
    for (int ct = 0; ct < NSL; ++ct) {
      int col = col0 + ct * 16 + r;
      float bv = bias[col], fv = fw[col];
#pragma unroll
      for (int rt = 0; rt < 2; ++rt)
#pragma unroll
        for (int q = 0; q < 4; ++q)
          pr[rt][q] += fmaxf(acc[rt][ct][q] + bv, 0.f) * fv;
    }
#pragma unroll
    for (int rt = 0; rt < 2; ++rt)
#pragma unroll
      for (int q = 0; q < 4; ++q) {
        pr[rt][q] += __shfl_xor(pr[rt][q], 1);
        pr[rt][q] += __shfl_xor(pr[rt][q], 2);
        pr[rt][q] += __shfl_xor(pr[rt][q], 4);
        pr[rt][q] += __shfl_xor(pr[rt][q], 8);
      }
    if (r < 4) {
#pragma unroll
      for (int rt = 0; rt < 2; ++rt) {
        float v = (r == 0) ? pr[rt][0] : (r == 1) ? pr[rt][1]
                : (r == 2) ? pr[rt][2] : pr[rt][3];
        dotb[(size_t)s * BATCH + row0 + w * 32 + rt * 16 + g * 4 + r] = v;
      }
    }
  }
}

// ---------- combine 5 slice partials + sigmoid ----------
__global__ void finish_kernel(const float* __restrict__ partial,
                              const float* __restrict__ dotb,
                              float* __restrict__ out) {
  int i = blockIdx.x * 256 + threadIdx.x;
  if (i < BATCH) {
    float x = partial[i] + dotb[i] + dotb[BATCH + i] + dotb[2 * BATCH + i]
            + dotb[3 * BATCH + i] + dotb[4 * BATCH + i];
    out[i] = 1.f / (1.f + expf(-x));
  }
}

extern "C" void kernel_launch(void* const* d_in, const int* in_sizes, int n_in,
                              void* d_out, int out_size, void* d_ws, size_t ws_size,
                              hipStream_t stream) {
  const int* xs = (const int*)d_in[0];
  const float* xd = (const float*)d_in[1];
  const float* emb1 = (const float*)d_in[2];
  const float* emb2 = (const float*)d_in[3];
  const float* wd = (const float*)d_in[4];
  const float* bias = (const float*)d_in[5];
  const float* w0 = (const float*)d_in[6];
  const float* b0 = (const float*)d_in[7];
  const float* w1 = (const float*)d_in[8];
  const float* b1 = (const float*)d_in[9];
  const float* w2 = (const float*)d_in[10];
  const float* b2 = (const float*)d_in[11];
  const float* fw = (const float*)d_in[12];
  float* out = (float*)d_out;

  char* ws = (char*)d_ws;
  float* partial = (float*)(ws + 0);        //  65536 B
  float* dotb    = (float*)(ws + 65536);    // 5*16384*4 = 327680 B
  bf16* wt0 = (bf16*)(ws + 393216);         // 416*448*2 = 372736
  bf16* wt1 = (bf16*)(ws + 765952);         // 416*416*2 = 346112
  bf16* wt2 = (bf16*)(ws + 1112064);        // 346112 -> 1458176
  bf16* h0  = (bf16*)(ws + 1458176);        // 16384*448*2 = 14680064
  bf16* h1  = (bf16*)(ws + 16138240);       // 16384*416*2 = 13631488
  bf16* h2  = (bf16*)(ws + 29769728);       // 13631488

  constexpr int LDS14 = 14 * CS * 64;       // 71680
  constexpr int LDS13 = 13 * CS * 64;       // 66560
  hipFuncSetAttribute((const void*)gemm_kernel<14, false>,
                      hipFuncAttributeMaxDynamicSharedMemorySize, LDS14);
  hipFuncSetAttribute((const void*)gemm_kernel<13, false>,
                      hipFuncAttributeMaxDynamicSharedMemorySize, LDS13);
  hipFuncSetAttribute((const void*)gemm_kernel<13, true>,
                      hipFuncAttributeMaxDynamicSharedMemorySize, LDS13);

  prep_kernel<<<2080, 256, 0, stream>>>(w0, w1, w2, wt0, wt1, wt2);
  gather_fm_kernel<<<BATCH / 4, 256, 0, stream>>>(xs, xd, emb1, emb2, wd, bias, h0, partial);

  gemm_kernel<14, false><<<640, 256, LDS14, stream>>>(h0, wt0, b0, h1, nullptr, nullptr);
  gemm_kernel<13, false><<<640, 256, LDS13, stream>>>(h1, wt1, b1, h2, nullptr, nullptr);
  gemm_kernel<13, true><<<640, 256, LDS13, stream>>>(h2, wt2, b2, nullptr, fw, dotb);

  finish_kernel<<<64, 256, 0, stream>>>(partial, dotb, out);
}